// Round 6
// baseline (73.380 us; speedup 1.0000x reference)
//
#include <hip/hip_runtime.h>

// RegistrationRecall: out = (sqrt(mean_n(min_m ||src_n - tgt_m||)^2) < 0.1) ? 1 : 0
// N = M = 8192, D = 3, fp32.
//
// R6: occupancy push. Grid = 512 source-groups x 2 target-halves = 1024 blocks
// = 4 blocks/CU = 4 waves/SIMD (vs 2 before). Each wave keeps S=4 sources
// (VALU:LDS ratio per iter unchanged at 224:36 cyc, LDS pipe ~64%). Tiles of
// 1024 targets double-buffered in LDS (24.6 KB/block), staged via
// global_load_lds(16B) with prefetch-before-compute. Tile loops fully unrolled
// so every ds_read_b128 is base(lane*48)+immediate-offset; per-source tree-min
// (v_min3-fusable) leaves 1 dependent min per iter. Exact direct-difference
// fp32 arithmetic preserved (rmse sits near the 0.1 threshold).

#define N_SRC 8192
#define N_TGT 8192
#define S     4
#define BLOCK 256
#define WAVES 4
#define SRC_PER_BLOCK (WAVES * S)          // 16
#define NSG   (N_SRC / SRC_PER_BLOCK)      // 512 source groups
#define NHALF 2
#define HALF_TGT (N_TGT / NHALF)           // 4096
#define TILE  1024
#define TILES_PER_HALF (HALF_TGT / TILE)   // 4
#define TPL   4
#define IT_PER_TILE (TILE / (64 * TPL))    // 4
#define F4_PER_THREAD ((TILE * 3 / 4) / BLOCK) // 3

#define GL2LDS16(gp, lp)                                                     \
    __builtin_amdgcn_global_load_lds(                                        \
        (const __attribute__((address_space(1))) void*)(const void*)(gp),    \
        (__attribute__((address_space(3))) void*)(void*)(lp), 16, 0, 0)

__global__ __launch_bounds__(BLOCK, 4) void knn_partial(const float* __restrict__ src,
                                                        const float* __restrict__ tgt,
                                                        float* __restrict__ minsq_out) {
    __shared__ float buf[2][TILE * 3];     // 2 x 12288 B

    const int tid  = threadIdx.x;
    const int lane = tid & 63;
    const int wave = tid >> 6;
    const int bx   = blockIdx.x;
    const int h    = bx >> 9;              // target half: 0 or 1
    const int sg   = bx & (NSG - 1);       // source group

    const float* thalf = tgt + h * HALF_TGT * 3;

    float sx[S], sy[S], sz[S], m[S];
    const float* sp = src + (sg * WAVES + wave) * S * 3;
    #pragma unroll
    for (int i = 0; i < S; ++i) {
        sx[i] = sp[3 * i + 0];
        sy[i] = sp[3 * i + 1];
        sz[i] = sp[3 * i + 2];
        m[i]  = 1e30f;
    }

    // ---- stage tile 0 ----
    {
        const float4* gs = (const float4*)thalf;
        float4* ls = (float4*)buf[0];
        #pragma unroll
        for (int k = 0; k < F4_PER_THREAD; ++k)
            GL2LDS16(gs + k * BLOCK + tid, ls + k * BLOCK + tid);
    }
    __syncthreads();

    for (int t = 0; t < TILES_PER_HALF; ++t) {
        // prefetch tile t+1 into the other buffer (async, drains at barrier)
        if (t + 1 < TILES_PER_HALF) {
            const float4* gs = (const float4*)(thalf + (t + 1) * TILE * 3);
            float4* ls = (float4*)buf[(t + 1) & 1];
            #pragma unroll
            for (int k = 0; k < F4_PER_THREAD; ++k)
                GL2LDS16(gs + k * BLOCK + tid, ls + k * BLOCK + tid);
        }

        const float* tile = buf[t & 1] + lane * (TPL * 3);  // base + imm offsets
        #pragma unroll
        for (int it = 0; it < IT_PER_TILE; ++it) {
            const float* tb = tile + it * (256 * 3);
            const float4 t0 = *(const float4*)(tb + 0);
            const float4 t1 = *(const float4*)(tb + 4);
            const float4 t2 = *(const float4*)(tb + 8);

            const float tx[TPL] = {t0.x, t0.w, t1.z, t2.y};
            const float ty[TPL] = {t0.y, t1.x, t1.w, t2.z};
            const float tz[TPL] = {t0.z, t1.y, t2.x, t2.w};

            #pragma unroll
            for (int i = 0; i < S; ++i) {
                float d2[TPL];
                #pragma unroll
                for (int j = 0; j < TPL; ++j) {
                    const float dx = sx[i] - tx[j];
                    const float dy = sy[i] - ty[j];
                    const float dz = sz[i] - tz[j];
                    d2[j] = dx * dx + dy * dy + dz * dz;
                }
                // tree-min (v_min3-fusable): 1 dependent update of m[i]
                m[i] = fminf(m[i], fminf(fminf(d2[0], d2[1]), fminf(d2[2], d2[3])));
            }
        }
        __syncthreads();
    }

    // butterfly min across the 64 lanes for each source
    #pragma unroll
    for (int off = 1; off < 64; off <<= 1) {
        #pragma unroll
        for (int i = 0; i < S; ++i)
            m[i] = fminf(m[i], __shfl_xor(m[i], off));
    }

    // per-source min-sq over this target half
    if (lane == 0) {
        float* o = minsq_out + h * N_SRC + (sg * WAVES + wave) * S;
        #pragma unroll
        for (int i = 0; i < S; ++i) o[i] = m[i];
    }
}

__global__ __launch_bounds__(256) void knn_finalize(const float* __restrict__ minsq,
                                                    float* __restrict__ out) {
    const int tid = threadIdx.x;
    float acc = 0.0f;
    #pragma unroll
    for (int k = 0; k < N_SRC / 256; ++k) {       // 32 sources per thread
        const int s = k * 256 + tid;
        const float mm = fminf(minsq[s], minsq[N_SRC + s]);
        const float d  = sqrtf(mm);               // reference rounding path
        acc += d * d;
    }

    #pragma unroll
    for (int off = 1; off < 64; off <<= 1)
        acc += __shfl_xor(acc, off);

    __shared__ float wsum[4];
    if ((tid & 63) == 0) wsum[tid >> 6] = acc;
    __syncthreads();
    if (tid == 0) {
        const float total = wsum[0] + wsum[1] + wsum[2] + wsum[3];
        const float rmse = sqrtf(total / (float)N_SRC);
        out[0] = (rmse < 0.1f) ? 1.0f : 0.0f;
    }
}

extern "C" void kernel_launch(void* const* d_in, const int* in_sizes, int n_in,
                              void* d_out, int out_size, void* d_ws, size_t ws_size,
                              hipStream_t stream) {
    const float* src = (const float*)d_in[0];
    const float* tgt = (const float*)d_in[1];
    float* minsq     = (float*)d_ws;     // 2 * 8192 floats, all written each launch
    float* out       = (float*)d_out;

    knn_partial<<<NSG * NHALF, BLOCK, 0, stream>>>(src, tgt, minsq);
    knn_finalize<<<1, 256, 0, stream>>>(minsq, out);
}